// Round 1
// baseline (106.974 us; speedup 1.0000x reference)
//
#include <hip/hip_runtime.h>
#include <hip/hip_bf16.h>

// Sizes (fixed by the reference)
#define BB 64
#define AA 128
#define FF 32
#define HH 64

// ws layout (float offsets)
//  hi_p  : [B*A][64]  (hi + pair_b1)           @ 0          (524288)
//  hj    : [B*A][64]                           @ 524288     (524288)
//  base_u: [B*A]                               @ 1048576    (8192)
//  util  : [B*A]                               @ 1056768    (8192)
//  W2t   : [64][64]   (pair_W2 transposed)     @ 1064960    (4096)
//  jlist : [B][128]   (int)                    @ 1069056    (8192)
//  jcnt  : [B]        (int)                    @ 1077248    (64)
// total ~4.31 MB

#define OFF_HIP   0
#define OFF_HJ    524288
#define OFF_BU    1048576
#define OFF_UTIL  1056768
#define OFF_W2T   1064960
#define OFF_JLIST 1069056
#define OFF_JCNT  1077248

// ---------------- Kernel 1: per-(b,a) features + j-lists + W2 transpose ----
__global__ __launch_bounds__(64)
void ddc_features(const float* __restrict__ X, const int* __restrict__ mask,
                  const float* __restrict__ bW1, const float* __restrict__ bb1,
                  const float* __restrict__ bW2, const float* __restrict__ bb2,
                  const float* __restrict__ bW3, const float* __restrict__ bb3,
                  const float* __restrict__ pW1, const float* __restrict__ pb1,
                  const float* __restrict__ pW2,
                  float* __restrict__ hi_p, float* __restrict__ hj,
                  float* __restrict__ base_u, float* __restrict__ W2t,
                  int* __restrict__ jlist, int* __restrict__ jcnt) {
    const int a = blockIdx.x, b = blockIdx.y, lane = threadIdx.x;
    const int row = b * AA + a;

    // X row is wave-uniform -> scalar loads
    const float* __restrict__ x = X + row * FF;
    float xr[FF];
#pragma unroll
    for (int f = 0; f < FF; ++f) xr[f] = x[f];

    float vhi = pb1[lane];      // fold pair_b1 into hi
    float vhj = 0.f;
    float v1  = bb1[lane];
#pragma unroll
    for (int f = 0; f < FF; ++f) {
        vhi = fmaf(xr[f], pW1[f * HH + lane], vhi);
        vhj = fmaf(xr[f], pW1[(FF + f) * HH + lane], vhj);
        v1  = fmaf(xr[f], bW1[f * HH + lane], v1);
    }
    v1 = fmaxf(v1, 0.f);

    // hb2 = relu(hb1 @ bW2 + bb2): broadcast hb1 across lanes via shuffles
    float v2 = bb2[lane];
#pragma unroll
    for (int k = 0; k < HH; ++k) {
        float hk = __shfl(v1, k);
        v2 = fmaf(hk, bW2[k * HH + lane], v2);
    }
    v2 = fmaxf(v2, 0.f);

    float bu = v2 * bW3[lane];
#pragma unroll
    for (int off = 32; off; off >>= 1) bu += __shfl_xor(bu, off);

    hi_p[row * HH + lane] = vhi;
    hj  [row * HH + lane] = vhj;
    if (lane == 0) base_u[row] = bu + bb3[0];

    // one block per b builds the compacted unmasked-j list
    if (a == 0) {
        int base0 = 0;
#pragma unroll
        for (int half = 0; half < 2; ++half) {
            int idx = half * 64 + lane;
            int m = mask[b * AA + idx];
            unsigned long long bal = __ballot(m != 0);
            int pos = __popcll(bal & ((1ull << lane) - 1ull));
            if (m) jlist[b * AA + base0 + pos] = idx;
            base0 += (int)__popcll(bal);
        }
        if (lane == 0) jcnt[b] = base0;
    }

    // one block transposes pair_W2 (columns contiguous for scalar loads)
    if (a == 1 && b == 0) {
#pragma unroll
        for (int n = 0; n < HH; ++n) W2t[n * HH + lane] = pW2[lane * HH + n];
    }
}

// ---------------- Kernel 2: pairwise MLP, lane = j ------------------------
__global__ __launch_bounds__(64)
void ddc_pairs(const float* __restrict__ hi_p, const float* __restrict__ hj,
               const float* __restrict__ base_u, const int* __restrict__ mask,
               const int* __restrict__ jlist, const int* __restrict__ jcnt,
               const float* __restrict__ W2t, const float* __restrict__ pb2,
               const float* __restrict__ pW3, const float* __restrict__ pb3,
               float* __restrict__ util) {
    const int i = blockIdx.x, b = blockIdx.y, lane = threadIdx.x;
    if (mask[b * AA + i] == 0) return;   // masked row: softmax kernel emits -1e9

    const float* __restrict__ hiP = hi_p + (b * AA + i) * HH;  // wave-uniform
    const int cnt = jcnt[b];
    const float b3v = pb3[0];

    float total = 0.f;
    for (int base = 0; base < cnt; base += 64) {
        const int jj = base + lane;
        const bool active = (jj < cnt);
        const int j = active ? jlist[b * AA + jj] : i;  // j==i path gets zeroed
        const float* __restrict__ hjP = hj + (b * AA + j) * HH;

        float h[HH];
#pragma unroll
        for (int k = 0; k < HH; ++k) h[k] = fmaxf(hiP[k] + hjP[k], 0.f);

        float pe = b3v;
        for (int n = 0; n < HH; ++n) {
            const float* __restrict__ w = W2t + n * HH;  // wave-uniform column
            float a0 = pb2[n], a1 = 0.f, a2 = 0.f, a3 = 0.f;
#pragma unroll
            for (int k = 0; k < HH; k += 4) {
                a0 = fmaf(h[k + 0], w[k + 0], a0);
                a1 = fmaf(h[k + 1], w[k + 1], a1);
                a2 = fmaf(h[k + 2], w[k + 2], a2);
                a3 = fmaf(h[k + 3], w[k + 3], a3);
            }
            const float acc = (a0 + a1) + (a2 + a3);
            pe = fmaf(fmaxf(acc, 0.f), pW3[n], pe);
        }
        if (!active || j == i) pe = 0.f;
        total += pe;
    }

#pragma unroll
    for (int off = 32; off; off >>= 1) total += __shfl_xor(total, off);
    if (lane == 0) util[b * AA + i] = base_u[b * AA + i] + total;
}

// ---------------- Kernel 3: per-b masked softmax over A=128 ---------------
__global__ __launch_bounds__(64)
void ddc_softmax(const float* __restrict__ util, const int* __restrict__ mask,
                 float* __restrict__ out) {
    const int b = blockIdx.x, lane = threadIdx.x;
    const int r0 = b * AA + lane, r1 = r0 + 64;
    const float u0 = (mask[r0] != 0) ? util[r0] : -1e9f;
    const float u1 = (mask[r1] != 0) ? util[r1] : -1e9f;

    float m = fmaxf(u0, u1);
#pragma unroll
    for (int off = 32; off; off >>= 1) m = fmaxf(m, __shfl_xor(m, off));

    const float e0 = __expf(u0 - m);
    const float e1 = __expf(u1 - m);
    float s = e0 + e1;
#pragma unroll
    for (int off = 32; off; off >>= 1) s += __shfl_xor(s, off);

    const float inv = 1.f / s;
    out[r0] = e0 * inv;
    out[r1] = e1 * inv;
}

extern "C" void kernel_launch(void* const* d_in, const int* in_sizes, int n_in,
                              void* d_out, int out_size, void* d_ws, size_t ws_size,
                              hipStream_t stream) {
    const float* X    = (const float*)d_in[0];
    const int*   mask = (const int*)  d_in[1];
    const float* bW1  = (const float*)d_in[2];
    const float* bb1  = (const float*)d_in[3];
    const float* bW2  = (const float*)d_in[4];
    const float* bb2  = (const float*)d_in[5];
    const float* bW3  = (const float*)d_in[6];
    const float* bb3  = (const float*)d_in[7];
    const float* pW1  = (const float*)d_in[8];
    const float* pb1  = (const float*)d_in[9];
    const float* pW2  = (const float*)d_in[10];
    const float* pb2  = (const float*)d_in[11];
    const float* pW3  = (const float*)d_in[12];
    const float* pb3  = (const float*)d_in[13];

    float* ws    = (float*)d_ws;
    float* hi_p  = ws + OFF_HIP;
    float* hjW   = ws + OFF_HJ;
    float* baseu = ws + OFF_BU;
    float* util  = ws + OFF_UTIL;
    float* W2t   = ws + OFF_W2T;
    int*   jlist = (int*)(ws + OFF_JLIST);
    int*   jcnt  = (int*)(ws + OFF_JCNT);

    float* out = (float*)d_out;

    dim3 g1(AA, BB);
    ddc_features<<<g1, 64, 0, stream>>>(X, mask, bW1, bb1, bW2, bb2, bW3, bb3,
                                        pW1, pb1, pW2,
                                        hi_p, hjW, baseu, W2t, jlist, jcnt);
    dim3 g2(AA, BB);
    ddc_pairs<<<g2, 64, 0, stream>>>(hi_p, hjW, baseu, mask, jlist, jcnt,
                                     W2t, pb2, pW3, pb3, util);
    ddc_softmax<<<BB, 64, 0, stream>>>(util, mask, out);
}